// Round 14
// baseline (679.804 us; speedup 1.0000x reference)
//
#include <hip/hip_runtime.h>
#include <hip/hip_bf16.h>

typedef short bf16x8 __attribute__((ext_vector_type(8)));
typedef float f32x4 __attribute__((ext_vector_type(4)));

__device__ __forceinline__ unsigned short f2bf(float f) {
  union { float f; unsigned int u; } x; x.f = f;
  return (unsigned short)((x.u + 0x7fffu + ((x.u >> 16) & 1u)) >> 16);
}
__device__ __forceinline__ float bf2f(unsigned short u) {
  union { unsigned int u; float f; } x; x.u = ((unsigned int)u) << 16;
  return x.f;
}
__device__ __forceinline__ void gload_lds16(const void* g, void* l) {
  __builtin_amdgcn_global_load_lds((const __attribute__((address_space(1))) void*)g,
                                   (__attribute__((address_space(3))) void*)l, 16, 0, 0);
}

// ---------------- cast x (f32 -> bf16), 4 elems/thread ----------------
__global__ void cast_f32_bf16(const float* __restrict__ src, unsigned short* __restrict__ dst) {
  int i = blockIdx.x * blockDim.x + threadIdx.x;
  float4 v = reinterpret_cast<const float4*>(src)[i];
  ushort4 o;
  o.x = f2bf(v.x); o.y = f2bf(v.y); o.z = f2bf(v.z); o.w = f2bf(v.w);
  reinterpret_cast<ushort4*>(dst)[i] = o;
}

// ------------- transpose+cast: src (R x C) f32 -> dst (C x R) bf16 -------------
__global__ void transpose_cast(const float* __restrict__ src, unsigned short* __restrict__ dst,
                               int R, int C) {
  __shared__ float tile[32][33];
  int c0 = blockIdx.x * 32, r0 = blockIdx.y * 32;
  int tx = threadIdx.x, ty = threadIdx.y;  // 32 x 8
#pragma unroll
  for (int i = 0; i < 4; ++i)
    tile[ty + i * 8][tx] = src[(size_t)(r0 + ty + i * 8) * C + (c0 + tx)];
  __syncthreads();
#pragma unroll
  for (int i = 0; i < 4; ++i)
    dst[(size_t)(c0 + ty + i * 8) * R + (r0 + tx)] = f2bf(tile[tx][ty + i * 8]);
}

// ====== 256x256 GEMM, ring-8, barrier/2-phases (R8 ledger) + frag-prefetch (R14) ======
// Stage order, slots, vmcnt(6), barrier placement: bit-identical to R8/R11 (proven).
// launch_bounds(512,1): real occupancy is LDS-bound at 1 block/CU anyway; (512,2)
// capped VGPR at 128 (R6/R9 post-mortems) which forbade frag prefetch.
// Static-role frag buffers: A0 = p0/p1 operand, A1 = p2/p3, B0 = p0/p2, B1 = p1/p3.
// Reads one phase ahead of use (each has >=1 phase of lgkm slack):
//   p0: MFMA(A0,B0) || rd B1       (B.h1(t):   staged 4t-4, drained vmcnt@p3(t-1), pub p3 bar)
//   p1: bar -> rd A1 || MFMA(A0,B1) (A.h1(t):  staged 4t-3, drained vmcnt@p0, pub p1 bar)
//   p2: rd A0' || MFMA(A1,B0)       (A.h0(t+1):staged 4t-2, drained vmcnt@p1, pub p1 bar)
//   p3: bar -> rd B0' || MFMA(A1,B1)(B.h0(t+1):staged 4t-1, drained vmcnt@p2, pub p3 bar)
// Tail prefetches of tile NT hit stale slots -> garbage into unused regs (harmless).
// Swizzle (T2): row r (128B) holds 16B-chunk s at byte (s^(r&7))*16.
// EPI 0: bf16 split into Q/K/V (B,T,D). EPI 1: f32 + bias.
template <int EPI>
__global__ __launch_bounds__(512, 1)
void gemm256(const unsigned short* __restrict__ A, const unsigned short* __restrict__ Bt,
             unsigned short* __restrict__ Qo, unsigned short* __restrict__ Ko,
             unsigned short* __restrict__ Vo, float* __restrict__ Cf,
             const float* __restrict__ bias, int M, int N, int K) {
  extern __shared__ __align__(16) char lds[];
  const int tid = threadIdx.x;
  const int lane = tid & 63, wid = tid >> 6;
  const int wm = wid >> 2, wn = wid & 3;
  const int fr = lane & 15, fq = lane >> 4;

  const int nbn = N >> 8;
  const int cpx = gridDim.x >> 3;
  const int id = blockIdx.x;
  const int sw = (id & 7) * cpx + (id >> 3);
  const int bm = sw / nbn, bn = sw % nbn;
  const int row0 = bm << 8, col0 = bn << 8;

  const int NT = K >> 6;

  // staging geometry: thread covers row srow (+64 for 2nd issue), 16B chunk, pre-swizzled
  const int srow = tid >> 3;
  const int scol = ((tid & 7) ^ (srow & 7)) << 3;  // elems

  const unsigned short* qA0 = A + (size_t)(row0 + srow) * K + scol;        // A.h0
  const unsigned short* qA1 = A + (size_t)(row0 + 128 + srow) * K + scol;  // A.h1
  const unsigned short* qB0 = Bt + (size_t)(col0 + srow) * K + scol;       // B.h0
  const unsigned short* qB1 = Bt + (size_t)(col0 + 128 + srow) * K + scol; // B.h1
  const unsigned short* dummy = A + (tid << 3);
  const size_t K64 = (size_t)64 * K;

  auto stageTo = [&](const unsigned short* src, int slot) {
    char* l0 = lds + slot * 16384 + tid * 16;
    gload_lds16(src, l0);
    gload_lds16(src + K64, l0 + 8192);
  };

  auto rdA = [&](const char* base, bf16x8 (&dst)[4][2]) {
#pragma unroll
    for (int i2 = 0; i2 < 4; ++i2)
#pragma unroll
      for (int ks = 0; ks < 2; ++ks) {
        const int byte = ((((wm * 4 + i2) * 16 + fr) * 128) + ks * 64 + fq * 16) ^ ((fr & 7) << 4);
        dst[i2][ks] = *reinterpret_cast<const bf16x8*>(base + byte);
      }
  };
  auto rdB = [&](const char* base, bf16x8 (&dst)[2][2]) {
#pragma unroll
    for (int j2 = 0; j2 < 2; ++j2)
#pragma unroll
      for (int ks = 0; ks < 2; ++ks) {
        const int byte = ((((wn * 2 + j2) * 16 + fr) * 128) + ks * 64 + fq * 16) ^ ((fr & 7) << 4);
        dst[j2][ks] = *reinterpret_cast<const bf16x8*>(base + byte);
      }
  };

  f32x4 acc[2][4][2][2] = {};
  bf16x8 A0[4][2], A1[4][2], B0[2][2], B1[2][2];

  // prologue: halves j=0..5 -> slots 0..5; vmcnt(6) drains j<=2; publish; pre-read tile0 A.h0/B.h0
  stageTo(qA0, 0); stageTo(qB0, 1); stageTo(qB1, 2); stageTo(qA1, 3);
  stageTo(qA0 + 64, 4); stageTo(qB0 + 64, 5);
  asm volatile("s_waitcnt vmcnt(6)" ::: "memory");
  asm volatile("s_barrier" ::: "memory");
  rdA(lds + 0 * 16384, A0);
  rdB(lds + 1 * 16384, B0);

  // body for one K-tile at slot base sb; stage slots s0..s3 (R8 order:
  // p0 stages B.h1(t+1), p1 A.h1(t+1), p2 A.h0(t+2), p3 B.h0(t+2)).
  auto body = [&](int sb, int s0, int s1, int s2, int s3,
                  const unsigned short* pB1, const unsigned short* pA1,
                  const unsigned short* pA0, const unsigned short* pB0,
                  bool g01, bool g23) {
    const char* Bs1 = lds + (sb + 2) * 16384;
    const char* As1 = lds + (sb + 3) * 16384;
    const char* nAs0 = lds + ((sb ^ 4) + 0) * 16384;
    const char* nBs0 = lds + ((sb ^ 4) + 1) * 16384;

    // ---- phase 0 (even): prefetch B1; MFMA(A0,B0) ----
    rdB(Bs1, B1);
    stageTo(g01 ? pB1 : dummy, s0);
    asm volatile("s_waitcnt vmcnt(6)" ::: "memory");
    __builtin_amdgcn_s_setprio(1);
#pragma unroll
    for (int i2 = 0; i2 < 4; ++i2)
#pragma unroll
      for (int j2 = 0; j2 < 2; ++j2)
#pragma unroll
        for (int ks = 0; ks < 2; ++ks)
          acc[0][i2][0][j2] =
              __builtin_amdgcn_mfma_f32_16x16x32_bf16(A0[i2][ks], B0[j2][ks], acc[0][i2][0][j2], 0, 0, 0);
    __builtin_amdgcn_s_setprio(0);

    // ---- phase 1 (odd, barrier): prefetch A1; MFMA(A0,B1) ----
    stageTo(g01 ? pA1 : dummy, s1);
    asm volatile("s_waitcnt vmcnt(6)" ::: "memory");
    asm volatile("s_barrier" ::: "memory");
    rdA(As1, A1);
    __builtin_amdgcn_s_setprio(1);
#pragma unroll
    for (int i2 = 0; i2 < 4; ++i2)
#pragma unroll
      for (int j2 = 0; j2 < 2; ++j2)
#pragma unroll
        for (int ks = 0; ks < 2; ++ks)
          acc[0][i2][1][j2] =
              __builtin_amdgcn_mfma_f32_16x16x32_bf16(A0[i2][ks], B1[j2][ks], acc[0][i2][1][j2], 0, 0, 0);
    __builtin_amdgcn_s_setprio(0);

    // ---- phase 2 (even): prefetch next-tile A0; MFMA(A1,B0) ----
    rdA(nAs0, A0);
    stageTo(g23 ? pA0 : dummy, s2);
    asm volatile("s_waitcnt vmcnt(6)" ::: "memory");
    __builtin_amdgcn_s_setprio(1);
#pragma unroll
    for (int i2 = 0; i2 < 4; ++i2)
#pragma unroll
      for (int j2 = 0; j2 < 2; ++j2)
#pragma unroll
        for (int ks = 0; ks < 2; ++ks)
          acc[1][i2][0][j2] =
              __builtin_amdgcn_mfma_f32_16x16x32_bf16(A1[i2][ks], B0[j2][ks], acc[1][i2][0][j2], 0, 0, 0);
    __builtin_amdgcn_s_setprio(0);

    // ---- phase 3 (odd, barrier): prefetch next-tile B0; MFMA(A1,B1) ----
    stageTo(g23 ? pB0 : dummy, s3);
    asm volatile("s_waitcnt vmcnt(6)" ::: "memory");
    asm volatile("s_barrier" ::: "memory");
    rdB(nBs0, B0);
    __builtin_amdgcn_s_setprio(1);
#pragma unroll
    for (int i2 = 0; i2 < 4; ++i2)
#pragma unroll
      for (int j2 = 0; j2 < 2; ++j2)
#pragma unroll
        for (int ks = 0; ks < 2; ++ks)
          acc[1][i2][1][j2] =
              __builtin_amdgcn_mfma_f32_16x16x32_bf16(A1[i2][ks], B1[j2][ks], acc[1][i2][1][j2], 0, 0, 0);
    __builtin_amdgcn_s_setprio(0);
  };

  const unsigned short* rB1 = qB1 + 64;
  const unsigned short* rA1 = qA1 + 64;
  const unsigned short* rA0 = qA0 + 128;
  const unsigned short* rB0 = qB0 + 128;

  for (int k = 0; k < NT; k += 2) {
    body(0, 6, 7, 0, 1, rB1, rA1, rA0, rB0, k < NT - 1, k < NT - 2);
    body(4, 2, 3, 4, 5, rB1 + 64, rA1 + 64, rA0 + 64, rB0 + 64, k < NT - 2, k < NT - 3);
    rB1 += 128; rA1 += 128; rA0 += 128; rB0 += 128;
  }

  asm volatile("s_waitcnt vmcnt(0)" ::: "memory");

  // epilogue: C/D layout col = lane&15, row = (lane>>4)*4 + r
#pragma unroll
  for (int mh = 0; mh < 2; ++mh)
#pragma unroll
    for (int i2 = 0; i2 < 4; ++i2) {
      const int rbase = row0 + (mh * 8 + wm * 4 + i2) * 16 + fq * 4;
#pragma unroll
      for (int nh = 0; nh < 2; ++nh)
#pragma unroll
        for (int j2 = 0; j2 < 2; ++j2) {
          const int col = col0 + (nh * 8 + wn * 2 + j2) * 16 + fr;
#pragma unroll
          for (int r = 0; r < 4; ++r) {
            const float v = acc[mh][i2][nh][j2][r];
            const int row = rbase + r;
            if (EPI == 0) {
              const int seg = col >> 11, cc = col & 2047;
              unsigned short* dst = (seg == 0) ? Qo : (seg == 1 ? Ko : Vo);
              dst[(size_t)row * 2048 + cc] = f2bf(v);
            } else {
              Cf[(size_t)row * N + col] = v + bias[col];
            }
          }
        }
    }
}

// ========== attention diag + V scale v4: 512 t-rows per block, ring-3 K staging ==========
// Grid 256: dispatch d -> head = d%64, tb = d/64 (4 blocks/head share an XCD -> K-head
// L2-resident). Ring-3 x 32 KB K buffers, stage 2 tiles ahead, per-iter vmcnt(4).
__global__ __launch_bounds__(512, 2)
void attn_diag_ov(const unsigned short* __restrict__ Q, const unsigned short* __restrict__ K,
                  const unsigned short* __restrict__ V, unsigned short* __restrict__ OV) {
  __shared__ __align__(16) char ks[3][128 * 256];  // 3 x 32 KB
  __shared__ float dlds[512];
  const int tid = threadIdx.x;
  const int lane = tid & 63, wid = tid >> 6;
  const int d = blockIdx.x;
  const int head = d & 63, tb = d >> 6;
  const int b = head >> 4, n = head & 15;
  const int t0 = tb << 9;                  // 512 rows per block
  const size_t hoff = (size_t)head << 18;  // head * 2048*128
  const unsigned short* Qh = Q + hoff;
  const unsigned short* Kh = K + hoff;
  const unsigned short* Vh = V + hoff;

  const int fr = lane & 15, fq = lane >> 4;
  const int g4 = fq << 2;
  const int qrow0 = t0 + wid * 64;

  bf16x8 qf[4][4];
#pragma unroll
  for (int m = 0; m < 4; ++m)
#pragma unroll
    for (int kk = 0; kk < 4; ++kk)
      qf[m][kk] = *reinterpret_cast<const bf16x8*>(
          Qh + (size_t)(qrow0 + m * 16 + fr) * 128 + kk * 32 + fq * 8);

  auto stageK = [&](int tile, int s) {
    const char* ksrc = (const char*)(Kh + ((size_t)(tile << 7) << 7));
#pragma unroll
    for (int i = 0; i < 4; ++i) {
      const int flat = i * 8192 + tid * 16;
      const int row = flat >> 8, c = (flat >> 4) & 15;
      const int sb = (row << 8) + ((c ^ (row & 15)) << 4);
      gload_lds16(ksrc + sb, &ks[s][0] + flat);
    }
  };

  float rsum[4][4] = {};
  float dnum[4][4] = {};
  const float scale = 0.02209708691207961f;  // 1/sqrt(2048)

  stageK(0, 0);
  stageK(1, 1);
  asm volatile("s_waitcnt vmcnt(4)" ::: "memory");  // tile0 landed
  asm volatile("s_barrier" ::: "memory");

  for (int t = 0; t < 16; ++t) {
    if (t < 14) stageK(t + 2, (t + 2) % 3);
    const char* buf = &ks[t % 3][0];
    const int jc = t << 7;
#pragma unroll
    for (int jt = 0; jt < 8; ++jt) {
      bf16x8 bfrag[4];
#pragma unroll
      for (int kk = 0; kk < 4; ++kk) {
        const int row = jt * 16 + fr;
        const int s = kk * 4 + fq;
        bfrag[kk] = *reinterpret_cast<const bf16x8*>(buf + (row << 8) + ((s ^ (row & 15)) << 4));
      }
      const int colj = jc + jt * 16 + fr;
#pragma unroll
      for (int m = 0; m < 4; ++m) {
        f32x4 acc = {0.f, 0.f, 0.f, 0.f};
#pragma unroll
        for (int kk = 0; kk < 4; ++kk)
          acc = __builtin_amdgcn_mfma_f32_16x16x32_bf16(qf[m][kk], bfrag[kk], acc, 0, 0, 0);
        const int rowt = qrow0 + m * 16 + g4;
#pragma unroll
        for (int r = 0; r < 4; ++r) {
          const float e = __expf(acc[r] * scale);
          rsum[m][r] += e;
          if (colj == rowt + r) dnum[m][r] = e;
        }
      }
    }
    asm volatile("s_waitcnt vmcnt(4)" ::: "memory");  // force tile t+1 landed
    asm volatile("s_barrier" ::: "memory");
  }

#pragma unroll
  for (int m = 0; m < 4; ++m)
#pragma unroll
    for (int r = 0; r < 4; ++r) {
#pragma unroll
      for (int s = 1; s < 16; s <<= 1) {
        rsum[m][r] += __shfl_xor(rsum[m][r], s, 64);
        dnum[m][r] += __shfl_xor(dnum[m][r], s, 64);
      }
      if (fr == 0) dlds[wid * 64 + m * 16 + g4 + r] = dnum[m][r] / rsum[m][r];
    }
  __syncthreads();

  const unsigned short* vsrc = Vh + ((size_t)t0 << 7);
  unsigned short* dst = OV + ((size_t)((b << 11) + t0)) * 2048 + (n << 7);
#pragma unroll
  for (int c = 0; c < 16; ++c) {
    const int flat = (c * 512 + tid) << 3;
    const int row = flat >> 7, col = flat & 127;
    bf16x8 v = *reinterpret_cast<const bf16x8*>(vsrc + flat);
    const float dd = dlds[row];
    bf16x8 o;
#pragma unroll
    for (int e = 0; e < 8; ++e)
      o[e] = (short)f2bf(bf2f((unsigned short)v[e]) * dd);
    *reinterpret_cast<bf16x8*>(dst + (size_t)row * 2048 + col) = o;
  }
}

extern "C" void kernel_launch(void* const* d_in, const int* in_sizes, int n_in,
                              void* d_out, int out_size, void* d_ws, size_t ws_size,
                              hipStream_t stream) {
  const float* x = (const float*)d_in[0];        // (4,2048,2048)
  const float* w_qkv = (const float*)d_in[1];    // (2048,6144)
  const float* w_proj = (const float*)d_in[2];   // (2048,2048)
  const float* b_proj = (const float*)d_in[3];   // (2048,)
  float* out = (float*)d_out;                    // (4,2048,2048) f32

  char* p = (char*)d_ws;
  unsigned short* Xb = (unsigned short*)p;     p += (size_t)8192 * 2048 * 2;
  unsigned short* WqkvT = (unsigned short*)p;  p += (size_t)6144 * 2048 * 2;
  unsigned short* WprojT = (unsigned short*)p; p += (size_t)2048 * 2048 * 2;
  unsigned short* Qb = (unsigned short*)p;     p += (size_t)8192 * 2048 * 2;
  unsigned short* Kb = (unsigned short*)p;     p += (size_t)8192 * 2048 * 2;
  unsigned short* Vb = (unsigned short*)p;     p += (size_t)8192 * 2048 * 2;
  unsigned short* OV = (unsigned short*)p;     p += (size_t)8192 * 2048 * 2;

  (void)hipFuncSetAttribute((const void*)gemm256<0>,
                            hipFuncAttributeMaxDynamicSharedMemorySize, 131072);
  (void)hipFuncSetAttribute((const void*)gemm256<1>,
                            hipFuncAttributeMaxDynamicSharedMemorySize, 131072);

  cast_f32_bf16<<<16384, 256, 0, stream>>>(x, Xb);
  transpose_cast<<<dim3(192, 64), dim3(32, 8), 0, stream>>>(w_qkv, WqkvT, 2048, 6144);
  transpose_cast<<<dim3(64, 64), dim3(32, 8), 0, stream>>>(w_proj, WprojT, 2048, 2048);

  // QKV = Xb (8192x2048) * WqkvT^T -> split bf16 Q/K/V (B,T,D)
  gemm256<0><<<dim3(32 * 24), 512, 131072, stream>>>(Xb, WqkvT, Qb, Kb, Vb, nullptr, nullptr,
                                                     8192, 6144, 2048);
  // diag softmax + V scale -> OV (8192x2048) bf16
  attn_diag_ov<<<dim3(256), 512, 0, stream>>>(Qb, Kb, Vb, OV);
  // out = OV * WprojT^T + b_proj (f32)
  gemm256<1><<<dim3(32 * 8), 512, 131072, stream>>>(OV, WprojT, nullptr, nullptr, nullptr, out,
                                                    b_proj, 8192, 2048, 2048);
}

// Round 15
// 339.388 us; speedup vs baseline: 2.0030x; 2.0030x over previous
//
#include <hip/hip_runtime.h>
#include <hip/hip_bf16.h>

typedef short bf16x8 __attribute__((ext_vector_type(8)));
typedef float f32x4 __attribute__((ext_vector_type(4)));

__device__ __forceinline__ unsigned short f2bf(float f) {
  union { float f; unsigned int u; } x; x.f = f;
  return (unsigned short)((x.u + 0x7fffu + ((x.u >> 16) & 1u)) >> 16);
}
__device__ __forceinline__ float bf2f(unsigned short u) {
  union { unsigned int u; float f; } x; x.u = ((unsigned int)u) << 16;
  return x.f;
}
__device__ __forceinline__ void gload_lds16(const void* g, void* l) {
  __builtin_amdgcn_global_load_lds((const __attribute__((address_space(1))) void*)g,
                                   (__attribute__((address_space(3))) void*)l, 16, 0, 0);
}

// ---------------- cast x (f32 -> bf16), 4 elems/thread ----------------
__global__ void cast_f32_bf16(const float* __restrict__ src, unsigned short* __restrict__ dst) {
  int i = blockIdx.x * blockDim.x + threadIdx.x;
  float4 v = reinterpret_cast<const float4*>(src)[i];
  ushort4 o;
  o.x = f2bf(v.x); o.y = f2bf(v.y); o.z = f2bf(v.z); o.w = f2bf(v.w);
  reinterpret_cast<ushort4*>(dst)[i] = o;
}

// ------------- transpose+cast: src (R x C) f32 -> dst (C x R) bf16 -------------
__global__ void transpose_cast(const float* __restrict__ src, unsigned short* __restrict__ dst,
                               int R, int C) {
  __shared__ float tile[32][33];
  int c0 = blockIdx.x * 32, r0 = blockIdx.y * 32;
  int tx = threadIdx.x, ty = threadIdx.y;  // 32 x 8
#pragma unroll
  for (int i = 0; i < 4; ++i)
    tile[ty + i * 8][tx] = src[(size_t)(r0 + ty + i * 8) * C + (c0 + tx)];
  __syncthreads();
#pragma unroll
  for (int i = 0; i < 4; ++i)
    dst[(size_t)(c0 + ty + i * 8) * R + (r0 + tx)] = f2bf(tile[tx][ty + i * 8]);
}

// ====== 256x256 GEMM, ring-8, barrier every 2 phases (R8 schedule, R11 addressing) ======
// 16x16x32 MFMA (R12: 32x32 frags = structural 4-way LDS bank conflict here).
// vmcnt(6) is the minimum legal wait; 2 barriers/tile is the ledger floor for 160KB LDS.
// Frag liveness MUST stay phase-local: unified VGPR/AGPR file gives 256 regs/lane at
// 2 waves/SIMD, acc owns 128 (AGPR) -> cross-barrier frag prefetch spills (R6, R14).
// launch_bounds note: 2nd arg behaves as blocks/CU (R9: (512,4) -> 64-VGPR spill).
// Swizzle (T2): row r (128B) holds 16B-chunk s at byte (s^(r&7))*16.
// EPI 0: bf16 split into Q/K/V (B,T,D). EPI 1: f32 + bias.
template <int EPI>
__global__ __launch_bounds__(512, 2)
void gemm256(const unsigned short* __restrict__ A, const unsigned short* __restrict__ Bt,
             unsigned short* __restrict__ Qo, unsigned short* __restrict__ Ko,
             unsigned short* __restrict__ Vo, float* __restrict__ Cf,
             const float* __restrict__ bias, int M, int N, int K) {
  extern __shared__ __align__(16) char lds[];
  const int tid = threadIdx.x;
  const int lane = tid & 63, wid = tid >> 6;
  const int wm = wid >> 2, wn = wid & 3;
  const int fr = lane & 15, fq = lane >> 4;

  const int nbn = N >> 8;
  const int cpx = gridDim.x >> 3;
  const int id = blockIdx.x;
  const int sw = (id & 7) * cpx + (id >> 3);
  const int bm = sw / nbn, bn = sw % nbn;
  const int row0 = bm << 8, col0 = bn << 8;

  const int NT = K >> 6;

  // staging geometry: thread covers row srow (+64 for 2nd issue), 16B chunk, pre-swizzled
  const int srow = tid >> 3;
  const int scol = ((tid & 7) ^ (srow & 7)) << 3;  // elems

  const unsigned short* qA0 = A + (size_t)(row0 + srow) * K + scol;        // A.h0
  const unsigned short* qA1 = A + (size_t)(row0 + 128 + srow) * K + scol;  // A.h1
  const unsigned short* qB0 = Bt + (size_t)(col0 + srow) * K + scol;       // B.h0
  const unsigned short* qB1 = Bt + (size_t)(col0 + 128 + srow) * K + scol; // B.h1
  const unsigned short* dummy = A + (tid << 3);
  const size_t K64 = (size_t)64 * K;

  auto stageTo = [&](const unsigned short* src, int slot) {
    char* l0 = lds + slot * 16384 + tid * 16;
    gload_lds16(src, l0);
    gload_lds16(src + K64, l0 + 8192);
  };

  auto rdA = [&](const char* base, bf16x8 (&dst)[4][2]) {
#pragma unroll
    for (int i2 = 0; i2 < 4; ++i2)
#pragma unroll
      for (int ks = 0; ks < 2; ++ks) {
        const int byte = ((((wm * 4 + i2) * 16 + fr) * 128) + ks * 64 + fq * 16) ^ ((fr & 7) << 4);
        dst[i2][ks] = *reinterpret_cast<const bf16x8*>(base + byte);
      }
  };
  auto rdB = [&](const char* base, bf16x8 (&dst)[2][2]) {
#pragma unroll
    for (int j2 = 0; j2 < 2; ++j2)
#pragma unroll
      for (int ks = 0; ks < 2; ++ks) {
        const int byte = ((((wn * 2 + j2) * 16 + fr) * 128) + ks * 64 + fq * 16) ^ ((fr & 7) << 4);
        dst[j2][ks] = *reinterpret_cast<const bf16x8*>(base + byte);
      }
  };

  f32x4 acc[2][4][2][2] = {};

  // prologue: halves j=0..5 -> slots 0..5 (tiles 0 and 1's first two halves)
  stageTo(qA0, 0); stageTo(qB0, 1); stageTo(qB1, 2); stageTo(qA1, 3);
  stageTo(qA0 + 64, 4); stageTo(qB0 + 64, 5);
  asm volatile("s_waitcnt vmcnt(6)" ::: "memory");
  asm volatile("s_barrier" ::: "memory");

  // body for one K-tile: reads slots sb..sb+3, stages into s0..s3 (R8 order:
  // p0 stages B.h1(t=k+1), p1 A.h1(t=k+1), p2 A.h0(t=k+2), p3 B.h0(t=k+2)).
  auto body = [&](int sb, int s0, int s1, int s2, int s3,
                  const unsigned short* pB1, const unsigned short* pA1,
                  const unsigned short* pA0, const unsigned short* pB0,
                  bool g01, bool g23) {
    const char* As0 = lds + (sb + 0) * 16384;
    const char* Bs0 = lds + (sb + 1) * 16384;
    const char* Bs1 = lds + (sb + 2) * 16384;
    const char* As1 = lds + (sb + 3) * 16384;
    bf16x8 a[4][2], b0[2][2], b1[2][2];

    // phase 0 (even)
    rdA(As0, a);
    rdB(Bs0, b0);
    stageTo(g01 ? pB1 : dummy, s0);
    asm volatile("s_waitcnt vmcnt(6)" ::: "memory");
    __builtin_amdgcn_s_setprio(1);
#pragma unroll
    for (int i2 = 0; i2 < 4; ++i2)
#pragma unroll
      for (int j2 = 0; j2 < 2; ++j2)
#pragma unroll
        for (int ks = 0; ks < 2; ++ks)
          acc[0][i2][0][j2] =
              __builtin_amdgcn_mfma_f32_16x16x32_bf16(a[i2][ks], b0[j2][ks], acc[0][i2][0][j2], 0, 0, 0);
    __builtin_amdgcn_s_setprio(0);

    // phase 1 (odd, barrier)
    rdB(Bs1, b1);
    stageTo(g01 ? pA1 : dummy, s1);
    asm volatile("s_waitcnt vmcnt(6)" ::: "memory");
    asm volatile("s_barrier" ::: "memory");
    __builtin_amdgcn_s_setprio(1);
#pragma unroll
    for (int i2 = 0; i2 < 4; ++i2)
#pragma unroll
      for (int j2 = 0; j2 < 2; ++j2)
#pragma unroll
        for (int ks = 0; ks < 2; ++ks)
          acc[0][i2][1][j2] =
              __builtin_amdgcn_mfma_f32_16x16x32_bf16(a[i2][ks], b1[j2][ks], acc[0][i2][1][j2], 0, 0, 0);
    __builtin_amdgcn_s_setprio(0);

    // phase 2 (even)
    rdA(As1, a);
    stageTo(g23 ? pA0 : dummy, s2);
    asm volatile("s_waitcnt vmcnt(6)" ::: "memory");
    __builtin_amdgcn_s_setprio(1);
#pragma unroll
    for (int i2 = 0; i2 < 4; ++i2)
#pragma unroll
      for (int j2 = 0; j2 < 2; ++j2)
#pragma unroll
        for (int ks = 0; ks < 2; ++ks)
          acc[1][i2][0][j2] =
              __builtin_amdgcn_mfma_f32_16x16x32_bf16(a[i2][ks], b0[j2][ks], acc[1][i2][0][j2], 0, 0, 0);
    __builtin_amdgcn_s_setprio(0);

    // phase 3 (odd, barrier)
    stageTo(g23 ? pB0 : dummy, s3);
    asm volatile("s_waitcnt vmcnt(6)" ::: "memory");
    asm volatile("s_barrier" ::: "memory");
    __builtin_amdgcn_s_setprio(1);
#pragma unroll
    for (int i2 = 0; i2 < 4; ++i2)
#pragma unroll
      for (int j2 = 0; j2 < 2; ++j2)
#pragma unroll
        for (int ks = 0; ks < 2; ++ks)
          acc[1][i2][1][j2] =
              __builtin_amdgcn_mfma_f32_16x16x32_bf16(a[i2][ks], b1[j2][ks], acc[1][i2][1][j2], 0, 0, 0);
    __builtin_amdgcn_s_setprio(0);
  };

  const unsigned short* rB1 = qB1 + 64;
  const unsigned short* rA1 = qA1 + 64;
  const unsigned short* rA0 = qA0 + 128;
  const unsigned short* rB0 = qB0 + 128;

  for (int k = 0; k < NT; k += 2) {
    body(0, 6, 7, 0, 1, rB1, rA1, rA0, rB0, k < NT - 1, k < NT - 2);
    body(4, 2, 3, 4, 5, rB1 + 64, rA1 + 64, rA0 + 64, rB0 + 64, k < NT - 2, k < NT - 3);
    rB1 += 128; rA1 += 128; rA0 += 128; rB0 += 128;
  }

  asm volatile("s_waitcnt vmcnt(0)" ::: "memory");

  // epilogue: C/D layout col = lane&15, row = (lane>>4)*4 + r
#pragma unroll
  for (int mh = 0; mh < 2; ++mh)
#pragma unroll
    for (int i2 = 0; i2 < 4; ++i2) {
      const int rbase = row0 + (mh * 8 + wm * 4 + i2) * 16 + fq * 4;
#pragma unroll
      for (int nh = 0; nh < 2; ++nh)
#pragma unroll
        for (int j2 = 0; j2 < 2; ++j2) {
          const int col = col0 + (nh * 8 + wn * 2 + j2) * 16 + fr;
#pragma unroll
          for (int r = 0; r < 4; ++r) {
            const float v = acc[mh][i2][nh][j2][r];
            const int row = rbase + r;
            if (EPI == 0) {
              const int seg = col >> 11, cc = col & 2047;
              unsigned short* dst = (seg == 0) ? Qo : (seg == 1 ? Ko : Vo);
              dst[(size_t)row * 2048 + cc] = f2bf(v);
            } else {
              Cf[(size_t)row * N + col] = v + bias[col];
            }
          }
        }
    }
}

// ========== attention diag + V scale v4: 512 t-rows per block, ring-3 K staging ==========
// Grid 256: dispatch d -> head = d%64, tb = d/64 (4 blocks/head share an XCD -> K-head
// L2-resident). Ring-3 x 32 KB K buffers, stage 2 tiles ahead, per-iter vmcnt(4)
// (allow newest tile's 4 loads in flight, force tile t+1 landed).
__global__ __launch_bounds__(512, 2)
void attn_diag_ov(const unsigned short* __restrict__ Q, const unsigned short* __restrict__ K,
                  const unsigned short* __restrict__ V, unsigned short* __restrict__ OV) {
  __shared__ __align__(16) char ks[3][128 * 256];  // 3 x 32 KB
  __shared__ float dlds[512];
  const int tid = threadIdx.x;
  const int lane = tid & 63, wid = tid >> 6;
  const int d = blockIdx.x;
  const int head = d & 63, tb = d >> 6;
  const int b = head >> 4, n = head & 15;
  const int t0 = tb << 9;                  // 512 rows per block
  const size_t hoff = (size_t)head << 18;  // head * 2048*128
  const unsigned short* Qh = Q + hoff;
  const unsigned short* Kh = K + hoff;
  const unsigned short* Vh = V + hoff;

  const int fr = lane & 15, fq = lane >> 4;
  const int g4 = fq << 2;
  const int qrow0 = t0 + wid * 64;

  // Q fragments direct from global: 4 m-groups x 4 k-chunks
  bf16x8 qf[4][4];
#pragma unroll
  for (int m = 0; m < 4; ++m)
#pragma unroll
    for (int kk = 0; kk < 4; ++kk)
      qf[m][kk] = *reinterpret_cast<const bf16x8*>(
          Qh + (size_t)(qrow0 + m * 16 + fr) * 128 + kk * 32 + fq * 8);

  auto stageK = [&](int tile, int s) {
    const char* ksrc = (const char*)(Kh + ((size_t)(tile << 7) << 7));
#pragma unroll
    for (int i = 0; i < 4; ++i) {
      const int flat = i * 8192 + tid * 16;
      const int row = flat >> 8, c = (flat >> 4) & 15;
      const int sb = (row << 8) + ((c ^ (row & 15)) << 4);
      gload_lds16(ksrc + sb, &ks[s][0] + flat);
    }
  };

  float rsum[4][4] = {};
  float dnum[4][4] = {};
  const float scale = 0.02209708691207961f;  // 1/sqrt(2048)

  stageK(0, 0);
  stageK(1, 1);
  asm volatile("s_waitcnt vmcnt(4)" ::: "memory");  // tile0 landed
  asm volatile("s_barrier" ::: "memory");

  for (int t = 0; t < 16; ++t) {
    if (t < 14) stageK(t + 2, (t + 2) % 3);
    const char* buf = &ks[t % 3][0];
    const int jc = t << 7;
#pragma unroll
    for (int jt = 0; jt < 8; ++jt) {
      bf16x8 bfrag[4];
#pragma unroll
      for (int kk = 0; kk < 4; ++kk) {
        const int row = jt * 16 + fr;
        const int s = kk * 4 + fq;
        bfrag[kk] = *reinterpret_cast<const bf16x8*>(buf + (row << 8) + ((s ^ (row & 15)) << 4));
      }
      const int colj = jc + jt * 16 + fr;
#pragma unroll
      for (int m = 0; m < 4; ++m) {
        f32x4 acc = {0.f, 0.f, 0.f, 0.f};
#pragma unroll
        for (int kk = 0; kk < 4; ++kk)
          acc = __builtin_amdgcn_mfma_f32_16x16x32_bf16(qf[m][kk], bfrag[kk], acc, 0, 0, 0);
        const int rowt = qrow0 + m * 16 + g4;
#pragma unroll
        for (int r = 0; r < 4; ++r) {
          const float e = __expf(acc[r] * scale);
          rsum[m][r] += e;
          if (colj == rowt + r) dnum[m][r] = e;
        }
      }
    }
    asm volatile("s_waitcnt vmcnt(4)" ::: "memory");  // force tile t+1 landed
    asm volatile("s_barrier" ::: "memory");
  }

  // reduce across the 16 fr-lanes (xor 1,2,4,8 keeps fq bits intact)
#pragma unroll
  for (int m = 0; m < 4; ++m)
#pragma unroll
    for (int r = 0; r < 4; ++r) {
#pragma unroll
      for (int s = 1; s < 16; s <<= 1) {
        rsum[m][r] += __shfl_xor(rsum[m][r], s, 64);
        dnum[m][r] += __shfl_xor(dnum[m][r], s, 64);
      }
      if (fr == 0) dlds[wid * 64 + m * 16 + g4 + r] = dnum[m][r] / rsum[m][r];
    }
  __syncthreads();

  // OV write: rows t0..t0+511, cols n*128..+128 of OV (8192 x 2048)
  const unsigned short* vsrc = Vh + ((size_t)t0 << 7);
  unsigned short* dst = OV + ((size_t)((b << 11) + t0)) * 2048 + (n << 7);
#pragma unroll
  for (int c = 0; c < 16; ++c) {
    const int flat = (c * 512 + tid) << 3;
    const int row = flat >> 7, col = flat & 127;
    bf16x8 v = *reinterpret_cast<const bf16x8*>(vsrc + flat);
    const float dd = dlds[row];
    bf16x8 o;
#pragma unroll
    for (int e = 0; e < 8; ++e)
      o[e] = (short)f2bf(bf2f((unsigned short)v[e]) * dd);
    *reinterpret_cast<bf16x8*>(dst + (size_t)row * 2048 + col) = o;
  }
}

extern "C" void kernel_launch(void* const* d_in, const int* in_sizes, int n_in,
                              void* d_out, int out_size, void* d_ws, size_t ws_size,
                              hipStream_t stream) {
  const float* x = (const float*)d_in[0];        // (4,2048,2048)
  const float* w_qkv = (const float*)d_in[1];    // (2048,6144)
  const float* w_proj = (const float*)d_in[2];   // (2048,2048)
  const float* b_proj = (const float*)d_in[3];   // (2048,)
  float* out = (float*)d_out;                    // (4,2048,2048) f32

  char* p = (char*)d_ws;
  unsigned short* Xb = (unsigned short*)p;     p += (size_t)8192 * 2048 * 2;
  unsigned short* WqkvT = (unsigned short*)p;  p += (size_t)6144 * 2048 * 2;
  unsigned short* WprojT = (unsigned short*)p; p += (size_t)2048 * 2048 * 2;
  unsigned short* Qb = (unsigned short*)p;     p += (size_t)8192 * 2048 * 2;
  unsigned short* Kb = (unsigned short*)p;     p += (size_t)8192 * 2048 * 2;
  unsigned short* Vb = (unsigned short*)p;     p += (size_t)8192 * 2048 * 2;
  unsigned short* OV = (unsigned short*)p;     p += (size_t)8192 * 2048 * 2;

  (void)hipFuncSetAttribute((const void*)gemm256<0>,
                            hipFuncAttributeMaxDynamicSharedMemorySize, 131072);
  (void)hipFuncSetAttribute((const void*)gemm256<1>,
                            hipFuncAttributeMaxDynamicSharedMemorySize, 131072);

  cast_f32_bf16<<<16384, 256, 0, stream>>>(x, Xb);
  transpose_cast<<<dim3(192, 64), dim3(32, 8), 0, stream>>>(w_qkv, WqkvT, 2048, 6144);
  transpose_cast<<<dim3(64, 64), dim3(32, 8), 0, stream>>>(w_proj, WprojT, 2048, 2048);

  // QKV = Xb (8192x2048) * WqkvT^T -> split bf16 Q/K/V (B,T,D)
  gemm256<0><<<dim3(32 * 24), 512, 131072, stream>>>(Xb, WqkvT, Qb, Kb, Vb, nullptr, nullptr,
                                                     8192, 6144, 2048);
  // diag softmax + V scale -> OV (8192x2048) bf16
  attn_diag_ov<<<dim3(256), 512, 0, stream>>>(Qb, Kb, Vb, OV);
  // out = OV * WprojT^T + b_proj (f32)
  gemm256<1><<<dim3(32 * 8), 512, 131072, stream>>>(OV, WprojT, nullptr, nullptr, nullptr, out,
                                                    b_proj, 8192, 2048, 2048);
}

// Round 16
// 337.392 us; speedup vs baseline: 2.0149x; 1.0059x over previous
//
#include <hip/hip_runtime.h>
#include <hip/hip_bf16.h>
#include <type_traits>

typedef short bf16x8 __attribute__((ext_vector_type(8)));
typedef float f32x4 __attribute__((ext_vector_type(4)));

__device__ __forceinline__ unsigned short f2bf(float f) {
  union { float f; unsigned int u; } x; x.f = f;
  return (unsigned short)((x.u + 0x7fffu + ((x.u >> 16) & 1u)) >> 16);
}
__device__ __forceinline__ float bf2f(unsigned short u) {
  union { unsigned int u; float f; } x; x.u = ((unsigned int)u) << 16;
  return x.f;
}
__device__ __forceinline__ void gload_lds16(const void* g, void* l) {
  __builtin_amdgcn_global_load_lds((const __attribute__((address_space(1))) void*)g,
                                   (__attribute__((address_space(3))) void*)l, 16, 0, 0);
}

// ====== fused preprocessing: cast x + transpose w_qkv + transpose w_proj ======
// blocks [0,16384): cast x f32->bf16 (4 elems/thread)
// blocks [16384, 28672): transpose+cast w_qkv (2048x6144 -> 6144x2048), 192x64 tiles
// blocks [28672, 32768): transpose+cast w_proj (2048x2048 -> 2048x2048), 64x64 tiles
__global__ void prep(const float* __restrict__ x, unsigned short* __restrict__ Xb,
                     const float* __restrict__ w_qkv, unsigned short* __restrict__ WqkvT,
                     const float* __restrict__ w_proj, unsigned short* __restrict__ WprojT) {
  const int bid = blockIdx.x;
  const int tid = threadIdx.x;
  if (bid < 16384) {
    const int i = bid * 256 + tid;
    float4 v = reinterpret_cast<const float4*>(x)[i];
    ushort4 o;
    o.x = f2bf(v.x); o.y = f2bf(v.y); o.z = f2bf(v.z); o.w = f2bf(v.w);
    reinterpret_cast<ushort4*>(Xb)[i] = o;
    return;
  }
  __shared__ float tile[32][33];
  const float* src;
  unsigned short* dst;
  int R, C, bx, by;
  if (bid < 28672) {
    const int b2 = bid - 16384;
    src = w_qkv; dst = WqkvT; R = 2048; C = 6144;
    bx = b2 % 192; by = b2 / 192;
  } else {
    const int b2 = bid - 28672;
    src = w_proj; dst = WprojT; R = 2048; C = 2048;
    bx = b2 % 64; by = b2 / 64;
  }
  const int c0 = bx * 32, r0 = by * 32;
  const int tx = tid & 31, ty = tid >> 5;  // 32 x 8
#pragma unroll
  for (int i = 0; i < 4; ++i)
    tile[ty + i * 8][tx] = src[(size_t)(r0 + ty + i * 8) * C + (c0 + tx)];
  __syncthreads();
#pragma unroll
  for (int i = 0; i < 4; ++i)
    dst[(size_t)(c0 + ty + i * 8) * R + (r0 + tx)] = f2bf(tile[tx][ty + i * 8]);
}

// ====== 256x256 GEMM, ring-8, barrier every 2 phases (R8 schedule, R11 addressing) ======
// 16x16x32 MFMA (R12: 32x32 frags = structural 4-way LDS bank conflict here).
// vmcnt(6) is the minimum legal wait; 2 barriers/tile is the ledger floor for 160KB LDS.
// Frag liveness MUST stay phase-local: unified VGPR/AGPR file gives 256 regs/lane at
// 2 waves/SIMD, acc owns 128 (AGPR) -> cross-barrier frag prefetch spills (R6, R14).
// launch_bounds note: 2nd arg behaves as blocks/CU (R9: (512,4) -> 64-VGPR spill).
// Swizzle (T2): row r (128B) holds 16B-chunk s at byte (s^(r&7))*16.
// EPI 0: bf16 split into Q/K/V (B,T,D). EPI 1: f32 + bias.
template <int EPI>
__global__ __launch_bounds__(512, 2)
void gemm256(const unsigned short* __restrict__ A, const unsigned short* __restrict__ Bt,
             unsigned short* __restrict__ Qo, unsigned short* __restrict__ Ko,
             unsigned short* __restrict__ Vo, float* __restrict__ Cf,
             const float* __restrict__ bias, int M, int N, int K) {
  extern __shared__ __align__(16) char lds[];
  const int tid = threadIdx.x;
  const int lane = tid & 63, wid = tid >> 6;
  const int wm = wid >> 2, wn = wid & 3;
  const int fr = lane & 15, fq = lane >> 4;

  const int nbn = N >> 8;
  const int cpx = gridDim.x >> 3;
  const int id = blockIdx.x;
  const int sw = (id & 7) * cpx + (id >> 3);
  const int bm = sw / nbn, bn = sw % nbn;
  const int row0 = bm << 8, col0 = bn << 8;

  const int NT = K >> 6;

  const int srow = tid >> 3;
  const int scol = ((tid & 7) ^ (srow & 7)) << 3;  // elems

  const unsigned short* qA0 = A + (size_t)(row0 + srow) * K + scol;        // A.h0
  const unsigned short* qA1 = A + (size_t)(row0 + 128 + srow) * K + scol;  // A.h1
  const unsigned short* qB0 = Bt + (size_t)(col0 + srow) * K + scol;       // B.h0
  const unsigned short* qB1 = Bt + (size_t)(col0 + 128 + srow) * K + scol; // B.h1
  const unsigned short* dummy = A + (tid << 3);
  const size_t K64 = (size_t)64 * K;

  auto stageTo = [&](const unsigned short* src, int slot) {
    char* l0 = lds + slot * 16384 + tid * 16;
    gload_lds16(src, l0);
    gload_lds16(src + K64, l0 + 8192);
  };

  auto rdA = [&](const char* base, bf16x8 (&dst)[4][2]) {
#pragma unroll
    for (int i2 = 0; i2 < 4; ++i2)
#pragma unroll
      for (int ks = 0; ks < 2; ++ks) {
        const int byte = ((((wm * 4 + i2) * 16 + fr) * 128) + ks * 64 + fq * 16) ^ ((fr & 7) << 4);
        dst[i2][ks] = *reinterpret_cast<const bf16x8*>(base + byte);
      }
  };
  auto rdB = [&](const char* base, bf16x8 (&dst)[2][2]) {
#pragma unroll
    for (int j2 = 0; j2 < 2; ++j2)
#pragma unroll
      for (int ks = 0; ks < 2; ++ks) {
        const int byte = ((((wn * 2 + j2) * 16 + fr) * 128) + ks * 64 + fq * 16) ^ ((fr & 7) << 4);
        dst[j2][ks] = *reinterpret_cast<const bf16x8*>(base + byte);
      }
  };

  f32x4 acc[2][4][2][2] = {};

  // prologue: halves j=0..5 -> slots 0..5 (tiles 0 and 1's first two halves)
  stageTo(qA0, 0); stageTo(qB0, 1); stageTo(qB1, 2); stageTo(qA1, 3);
  stageTo(qA0 + 64, 4); stageTo(qB0 + 64, 5);
  asm volatile("s_waitcnt vmcnt(6)" ::: "memory");
  asm volatile("s_barrier" ::: "memory");

  auto body = [&](int sb, int s0, int s1, int s2, int s3,
                  const unsigned short* pB1, const unsigned short* pA1,
                  const unsigned short* pA0, const unsigned short* pB0,
                  bool g01, bool g23) {
    const char* As0 = lds + (sb + 0) * 16384;
    const char* Bs0 = lds + (sb + 1) * 16384;
    const char* Bs1 = lds + (sb + 2) * 16384;
    const char* As1 = lds + (sb + 3) * 16384;
    bf16x8 a[4][2], b0[2][2], b1[2][2];

    // phase 0 (even)
    rdA(As0, a);
    rdB(Bs0, b0);
    stageTo(g01 ? pB1 : dummy, s0);
    asm volatile("s_waitcnt vmcnt(6)" ::: "memory");
    __builtin_amdgcn_s_setprio(1);
#pragma unroll
    for (int i2 = 0; i2 < 4; ++i2)
#pragma unroll
      for (int j2 = 0; j2 < 2; ++j2)
#pragma unroll
        for (int ks = 0; ks < 2; ++ks)
          acc[0][i2][0][j2] =
              __builtin_amdgcn_mfma_f32_16x16x32_bf16(a[i2][ks], b0[j2][ks], acc[0][i2][0][j2], 0, 0, 0);
    __builtin_amdgcn_s_setprio(0);

    // phase 1 (odd, barrier)
    rdB(Bs1, b1);
    stageTo(g01 ? pA1 : dummy, s1);
    asm volatile("s_waitcnt vmcnt(6)" ::: "memory");
    asm volatile("s_barrier" ::: "memory");
    __builtin_amdgcn_s_setprio(1);
#pragma unroll
    for (int i2 = 0; i2 < 4; ++i2)
#pragma unroll
      for (int j2 = 0; j2 < 2; ++j2)
#pragma unroll
        for (int ks = 0; ks < 2; ++ks)
          acc[0][i2][1][j2] =
              __builtin_amdgcn_mfma_f32_16x16x32_bf16(a[i2][ks], b1[j2][ks], acc[0][i2][1][j2], 0, 0, 0);
    __builtin_amdgcn_s_setprio(0);

    // phase 2 (even)
    rdA(As1, a);
    stageTo(g23 ? pA0 : dummy, s2);
    asm volatile("s_waitcnt vmcnt(6)" ::: "memory");
    __builtin_amdgcn_s_setprio(1);
#pragma unroll
    for (int i2 = 0; i2 < 4; ++i2)
#pragma unroll
      for (int j2 = 0; j2 < 2; ++j2)
#pragma unroll
        for (int ks = 0; ks < 2; ++ks)
          acc[1][i2][0][j2] =
              __builtin_amdgcn_mfma_f32_16x16x32_bf16(a[i2][ks], b0[j2][ks], acc[1][i2][0][j2], 0, 0, 0);
    __builtin_amdgcn_s_setprio(0);

    // phase 3 (odd, barrier)
    stageTo(g23 ? pB0 : dummy, s3);
    asm volatile("s_waitcnt vmcnt(6)" ::: "memory");
    asm volatile("s_barrier" ::: "memory");
    __builtin_amdgcn_s_setprio(1);
#pragma unroll
    for (int i2 = 0; i2 < 4; ++i2)
#pragma unroll
      for (int j2 = 0; j2 < 2; ++j2)
#pragma unroll
        for (int ks = 0; ks < 2; ++ks)
          acc[1][i2][1][j2] =
              __builtin_amdgcn_mfma_f32_16x16x32_bf16(a[i2][ks], b1[j2][ks], acc[1][i2][1][j2], 0, 0, 0);
    __builtin_amdgcn_s_setprio(0);
  };

  const unsigned short* rB1 = qB1 + 64;
  const unsigned short* rA1 = qA1 + 64;
  const unsigned short* rA0 = qA0 + 128;
  const unsigned short* rB0 = qB0 + 128;

  for (int k = 0; k < NT; k += 2) {
    body(0, 6, 7, 0, 1, rB1, rA1, rA0, rB0, k < NT - 1, k < NT - 2);
    body(4, 2, 3, 4, 5, rB1 + 64, rA1 + 64, rA0 + 64, rB0 + 64, k < NT - 2, k < NT - 3);
    rB1 += 128; rA1 += 128; rA0 += 128; rB0 += 128;
  }

  asm volatile("s_waitcnt vmcnt(0)" ::: "memory");

  // epilogue: C/D layout col = lane&15, row = (lane>>4)*4 + r
#pragma unroll
  for (int mh = 0; mh < 2; ++mh)
#pragma unroll
    for (int i2 = 0; i2 < 4; ++i2) {
      const int rbase = row0 + (mh * 8 + wm * 4 + i2) * 16 + fq * 4;
#pragma unroll
      for (int nh = 0; nh < 2; ++nh)
#pragma unroll
        for (int j2 = 0; j2 < 2; ++j2) {
          const int col = col0 + (nh * 8 + wn * 2 + j2) * 16 + fr;
#pragma unroll
          for (int r = 0; r < 4; ++r) {
            const float v = acc[mh][i2][nh][j2][r];
            const int row = rbase + r;
            if (EPI == 0) {
              const int seg = col >> 11, cc = col & 2047;
              unsigned short* dst = (seg == 0) ? Qo : (seg == 1 ? Ko : Vo);
              dst[(size_t)row * 2048 + cc] = f2bf(v);
            } else {
              Cf[(size_t)row * N + col] = v + bias[col];
            }
          }
        }
    }
}

// ========== attention diag + V scale v5: 512 t-rows per block, ring-3, diag-split ==========
// Grid 256: dispatch d -> head = d%64, tb = d/64 (4 blocks/head share an XCD -> K-head
// L2-resident). Ring-3 x 32 KB K buffers, stage 2 tiles ahead, per-iter vmcnt(4).
// Each wave's 64 q-rows meet the diagonal in EXACTLY one K-tile (tdiag = qrow0>>7;
// qrow0 mod 128 in {0,64} so the 64-row span never straddles a 128-col tile) ->
// only that tile runs the diag compare (15/16 tiles drop 16 cmp+sel per m per jt).
__global__ __launch_bounds__(512, 2)
void attn_diag_ov(const unsigned short* __restrict__ Q, const unsigned short* __restrict__ K,
                  const unsigned short* __restrict__ V, unsigned short* __restrict__ OV) {
  __shared__ __align__(16) char ks[3][128 * 256];  // 3 x 32 KB
  __shared__ float dlds[512];
  const int tid = threadIdx.x;
  const int lane = tid & 63, wid = tid >> 6;
  const int d = blockIdx.x;
  const int head = d & 63, tb = d >> 6;
  const int b = head >> 4, n = head & 15;
  const int t0 = tb << 9;                  // 512 rows per block
  const size_t hoff = (size_t)head << 18;  // head * 2048*128
  const unsigned short* Qh = Q + hoff;
  const unsigned short* Kh = K + hoff;
  const unsigned short* Vh = V + hoff;

  const int fr = lane & 15, fq = lane >> 4;
  const int g4 = fq << 2;
  const int qrow0 = t0 + wid * 64;
  const int tdiag = qrow0 >> 7;            // the single K-tile with this wave's diagonal

  // Q fragments direct from global: 4 m-groups x 4 k-chunks
  bf16x8 qf[4][4];
#pragma unroll
  for (int m = 0; m < 4; ++m)
#pragma unroll
    for (int kk = 0; kk < 4; ++kk)
      qf[m][kk] = *reinterpret_cast<const bf16x8*>(
          Qh + (size_t)(qrow0 + m * 16 + fr) * 128 + kk * 32 + fq * 8);

  auto stageK = [&](int tile, int s) {
    const char* ksrc = (const char*)(Kh + ((size_t)(tile << 7) << 7));
#pragma unroll
    for (int i = 0; i < 4; ++i) {
      const int flat = i * 8192 + tid * 16;
      const int row = flat >> 8, c = (flat >> 4) & 15;
      const int sb = (row << 8) + ((c ^ (row & 15)) << 4);
      gload_lds16(ksrc + sb, &ks[s][0] + flat);
    }
  };

  float rsum[4][4] = {};
  float dnum[4][4] = {};
  const float scale = 0.02209708691207961f;  // 1/sqrt(2048)

  auto doTile = [&](int t, auto wd) {
    const char* buf = &ks[t % 3][0];
    const int jc = t << 7;
#pragma unroll
    for (int jt = 0; jt < 8; ++jt) {
      bf16x8 bfrag[4];
#pragma unroll
      for (int kk = 0; kk < 4; ++kk) {
        const int row = jt * 16 + fr;
        const int s = kk * 4 + fq;
        bfrag[kk] = *reinterpret_cast<const bf16x8*>(buf + (row << 8) + ((s ^ (row & 15)) << 4));
      }
#pragma unroll
      for (int m = 0; m < 4; ++m) {
        f32x4 acc = {0.f, 0.f, 0.f, 0.f};
#pragma unroll
        for (int kk = 0; kk < 4; ++kk)
          acc = __builtin_amdgcn_mfma_f32_16x16x32_bf16(qf[m][kk], bfrag[kk], acc, 0, 0, 0);
#pragma unroll
        for (int r = 0; r < 4; ++r) {
          const float e = __expf(acc[r] * scale);
          rsum[m][r] += e;
          if constexpr (decltype(wd)::value) {
            const int colj = jc + jt * 16 + fr;
            const int rowt = qrow0 + m * 16 + g4;
            if (colj == rowt + r) dnum[m][r] = e;
          }
        }
      }
    }
  };

  stageK(0, 0);
  stageK(1, 1);
  asm volatile("s_waitcnt vmcnt(4)" ::: "memory");  // tile0 landed
  asm volatile("s_barrier" ::: "memory");

  for (int t = 0; t < 16; ++t) {
    if (t < 14) stageK(t + 2, (t + 2) % 3);
    if (t == tdiag) doTile(t, std::true_type{});
    else            doTile(t, std::false_type{});
    asm volatile("s_waitcnt vmcnt(4)" ::: "memory");  // force tile t+1 landed
    asm volatile("s_barrier" ::: "memory");
  }

  // reduce across the 16 fr-lanes (xor 1,2,4,8 keeps fq bits intact)
#pragma unroll
  for (int m = 0; m < 4; ++m)
#pragma unroll
    for (int r = 0; r < 4; ++r) {
#pragma unroll
      for (int s = 1; s < 16; s <<= 1) {
        rsum[m][r] += __shfl_xor(rsum[m][r], s, 64);
        dnum[m][r] += __shfl_xor(dnum[m][r], s, 64);
      }
      if (fr == 0) dlds[wid * 64 + m * 16 + g4 + r] = dnum[m][r] / rsum[m][r];
    }
  __syncthreads();

  // OV write: rows t0..t0+511, cols n*128..+128 of OV (8192 x 2048)
  const unsigned short* vsrc = Vh + ((size_t)t0 << 7);
  unsigned short* dst = OV + ((size_t)((b << 11) + t0)) * 2048 + (n << 7);
#pragma unroll
  for (int c = 0; c < 16; ++c) {
    const int flat = (c * 512 + tid) << 3;
    const int row = flat >> 7, col = flat & 127;
    bf16x8 v = *reinterpret_cast<const bf16x8*>(vsrc + flat);
    const float dd = dlds[row];
    bf16x8 o;
#pragma unroll
    for (int e = 0; e < 8; ++e)
      o[e] = (short)f2bf(bf2f((unsigned short)v[e]) * dd);
    *reinterpret_cast<bf16x8*>(dst + (size_t)row * 2048 + col) = o;
  }
}

extern "C" void kernel_launch(void* const* d_in, const int* in_sizes, int n_in,
                              void* d_out, int out_size, void* d_ws, size_t ws_size,
                              hipStream_t stream) {
  const float* x = (const float*)d_in[0];        // (4,2048,2048)
  const float* w_qkv = (const float*)d_in[1];    // (2048,6144)
  const float* w_proj = (const float*)d_in[2];   // (2048,2048)
  const float* b_proj = (const float*)d_in[3];   // (2048,)
  float* out = (float*)d_out;                    // (4,2048,2048) f32

  char* p = (char*)d_ws;
  unsigned short* Xb = (unsigned short*)p;     p += (size_t)8192 * 2048 * 2;
  unsigned short* WqkvT = (unsigned short*)p;  p += (size_t)6144 * 2048 * 2;
  unsigned short* WprojT = (unsigned short*)p; p += (size_t)2048 * 2048 * 2;
  unsigned short* Qb = (unsigned short*)p;     p += (size_t)8192 * 2048 * 2;
  unsigned short* Kb = (unsigned short*)p;     p += (size_t)8192 * 2048 * 2;
  unsigned short* Vb = (unsigned short*)p;     p += (size_t)8192 * 2048 * 2;
  unsigned short* OV = (unsigned short*)p;     p += (size_t)8192 * 2048 * 2;

  (void)hipFuncSetAttribute((const void*)gemm256<0>,
                            hipFuncAttributeMaxDynamicSharedMemorySize, 131072);
  (void)hipFuncSetAttribute((const void*)gemm256<1>,
                            hipFuncAttributeMaxDynamicSharedMemorySize, 131072);

  // fused cast + transposes (one dispatch; blocks: 16384 cast, 12288 WqkvT, 4096 WprojT)
  prep<<<32768, 256, 0, stream>>>(x, Xb, w_qkv, WqkvT, w_proj, WprojT);

  // QKV = Xb (8192x2048) * WqkvT^T -> split bf16 Q/K/V (B,T,D)
  gemm256<0><<<dim3(32 * 24), 512, 131072, stream>>>(Xb, WqkvT, Qb, Kb, Vb, nullptr, nullptr,
                                                     8192, 6144, 2048);
  // diag softmax + V scale -> OV (8192x2048) bf16
  attn_diag_ov<<<dim3(256), 512, 0, stream>>>(Qb, Kb, Vb, OV);
  // out = OV * WprojT^T + b_proj (f32)
  gemm256<1><<<dim3(32 * 8), 512, 131072, stream>>>(OV, WprojT, nullptr, nullptr, nullptr, out,
                                                    b_proj, 8192, 2048, 2048);
}